// Round 5
// baseline (330.281 us; speedup 1.0000x reference)
//
#include <hip/hip_runtime.h>

#define BATCH   1048576
#define IN_DIM  64
#define OUT_DIM 16

// ---------------------------------------------------------------------------
// Kernel 1: G = (A A^T)^-1  (16x16), C = G*A (16x64), written to workspace.
// Single block, 256 threads. Gauss-Jordan with partial pivoting in LDS.
// (validated in rounds 1-4)
// ---------------------------------------------------------------------------
__global__ __launch_bounds__(256) void precompute_kernel(
    const float* __restrict__ A, float* __restrict__ GC)
{
    __shared__ float sA[16][64];
    __shared__ float M[16][32];   // [S | I]
    __shared__ float fac[16];
    __shared__ int piv;

    const int tid = threadIdx.x;

    for (int i = tid; i < 1024; i += 256) sA[i >> 6][i & 63] = A[i];
    __syncthreads();

    {
        const int i = tid >> 4, j = tid & 15;
        float s = 0.f;
        #pragma unroll
        for (int k = 0; k < 64; ++k) s = fmaf(sA[i][k], sA[j][k], s);
        M[i][j] = s;
        M[i][16 + j] = (i == j) ? 1.f : 0.f;
    }
    __syncthreads();

    for (int p = 0; p < 16; ++p) {
        if (tid == 0) {
            int best = p;
            float bv = fabsf(M[p][p]);
            for (int r = p + 1; r < 16; ++r) {
                float v = fabsf(M[r][p]);
                if (v > bv) { bv = v; best = r; }
            }
            piv = best;
        }
        __syncthreads();
        if (tid < 32) {
            const int pr = piv;
            if (pr != p) { float t = M[p][tid]; M[p][tid] = M[pr][tid]; M[pr][tid] = t; }
        }
        __syncthreads();
        const float pv = M[p][p];
        __syncthreads();
        if (tid < 32) M[p][tid] *= (1.0f / pv);
        __syncthreads();
        if (tid < 16) fac[tid] = M[tid][p];
        __syncthreads();
        for (int e = tid; e < 512; e += 256) {
            const int r = e >> 5, c = e & 31;
            if (r != p) M[r][c] = fmaf(-fac[r], M[p][c], M[r][c]);
        }
        __syncthreads();
    }

    // G -> GC[0:256)
    {
        const int i = tid >> 4, j = tid & 15;
        GC[tid] = M[i][16 + j];
    }
    // C = G*A -> GC[256:1280)
    for (int e = tid; e < 1024; e += 256) {
        const int i = e >> 6, k = e & 63;
        float s = 0.f;
        #pragma unroll
        for (int j = 0; j < 16; ++j) s = fmaf(M[i][16 + j], sA[j][k], s);
        GC[256 + e] = s;
    }
}

// ---------------------------------------------------------------------------
// Kernel 2: x = y - C^T (A y - b), FOUR lanes per row.
// Lane c of a quad owns float4 slots {c, c+4, c+8, c+12} of the row, so each
// global y/out wave-instruction is one contiguous 1 KB access. Live set per
// lane is ~45 VGPR by construction (round-4 lesson: 64-f32 rows forced the
// compiler into reload chains). Matrix reads are 4-distinct-address L1 hits
// (one 64B line per instruction). Quad shfl_xor butterfly completes the dot.
// ---------------------------------------------------------------------------
__global__ __launch_bounds__(256, 6) void apply_kernel(
    const float* __restrict__ y, const float* __restrict__ b,
    const float* __restrict__ A, const float* __restrict__ GC,
    float* __restrict__ out)
{
    const int tid = threadIdx.x;
    const int c = tid & 3;                                   // quad lane
    const size_t row = ((size_t)blockIdx.x * 256 + tid) >> 2;

    const float4* __restrict__ y4 = reinterpret_cast<const float4*>(y) + row * 16;
    const float4* __restrict__ A4 = reinterpret_cast<const float4*>(A);
    const float4* __restrict__ C4 = reinterpret_cast<const float4*>(GC + 256);

    // Per-lane row data: 4 float4 = 16 floats, plus this lane's b quarter.
    float4 yv0 = y4[c + 0];
    float4 yv1 = y4[c + 4];
    float4 yv2 = y4[c + 8];
    float4 yv3 = y4[c + 12];
    const float4 bl = reinterpret_cast<const float4*>(b)[row * 4 + c];

    // Partial t[j] = sum over this lane's 16 k of A[j][k]*y[k], minus b[j]
    // folded by the owning lane (exactly one lane per quad per j).
    float t[16];
    #pragma unroll
    for (int j = 0; j < 16; ++j) {
        const float bj = ((j & 3) == 0) ? bl.x :
                         ((j & 3) == 1) ? bl.y :
                         ((j & 3) == 2) ? bl.z : bl.w;
        float acc = (c == (j >> 2)) ? -bj : 0.f;
        const float4 a0 = A4[j * 16 + c + 0];
        const float4 a1 = A4[j * 16 + c + 4];
        const float4 a2 = A4[j * 16 + c + 8];
        const float4 a3 = A4[j * 16 + c + 12];
        acc = fmaf(a0.x, yv0.x, acc);
        acc = fmaf(a0.y, yv0.y, acc);
        acc = fmaf(a0.z, yv0.z, acc);
        acc = fmaf(a0.w, yv0.w, acc);
        acc = fmaf(a1.x, yv1.x, acc);
        acc = fmaf(a1.y, yv1.y, acc);
        acc = fmaf(a1.z, yv1.z, acc);
        acc = fmaf(a1.w, yv1.w, acc);
        acc = fmaf(a2.x, yv2.x, acc);
        acc = fmaf(a2.y, yv2.y, acc);
        acc = fmaf(a2.z, yv2.z, acc);
        acc = fmaf(a2.w, yv2.w, acc);
        acc = fmaf(a3.x, yv3.x, acc);
        acc = fmaf(a3.y, yv3.y, acc);
        acc = fmaf(a3.z, yv3.z, acc);
        acc = fmaf(a3.w, yv3.w, acc);
        t[j] = acc;
    }

    // Quad butterfly: every lane gets full t[j] = A[j]·y - b[j].
    #pragma unroll
    for (int j = 0; j < 16; ++j) {
        t[j] += __shfl_xor(t[j], 1);
        t[j] += __shfl_xor(t[j], 2);
    }

    // x_k = y_k - sum_j t[j] * C[j][k] for this lane's 16 k.
    float4* __restrict__ o4 = reinterpret_cast<float4*>(out) + row * 16;
    #pragma unroll
    for (int q = 0; q < 4; ++q) {
        float4 x = (q == 0) ? yv0 : (q == 1) ? yv1 : (q == 2) ? yv2 : yv3;
        #pragma unroll
        for (int j = 0; j < 16; ++j) {
            const float4 cc = C4[j * 16 + c + 4 * q];
            x.x = fmaf(-cc.x, t[j], x.x);
            x.y = fmaf(-cc.y, t[j], x.y);
            x.z = fmaf(-cc.z, t[j], x.z);
            x.w = fmaf(-cc.w, t[j], x.w);
        }
        o4[c + 4 * q] = x;
    }
}

// ---------------------------------------------------------------------------
extern "C" void kernel_launch(void* const* d_in, const int* in_sizes, int n_in,
                              void* d_out, int out_size, void* d_ws, size_t ws_size,
                              hipStream_t stream) {
    const float* y = (const float*)d_in[0];   // (1048576, 64)
    const float* A = (const float*)d_in[1];   // (16, 64)
    const float* b = (const float*)d_in[2];   // (1048576, 16)
    float* out = (float*)d_out;               // (1048576, 64)
    float* GC  = (float*)d_ws;                // 1280 floats: G(256) + C(1024)

    precompute_kernel<<<1, 256, 0, stream>>>(A, GC);
    // 4 lanes per row: 4M threads total.
    apply_kernel<<<(BATCH * 4) / 256, 256, 0, stream>>>(y, b, A, GC, out);
}